// Round 1
// baseline (152763.538 us; speedup 1.0000x reference)
//
#include <hip/hip_runtime.h>
#include <math.h>

#define Bb 64
#define Ll 1024
#define Dd 512
#define G4 2048      // 4*D
#define PART_STRIDE 520

__device__ __forceinline__ float hsig(float v){ return fminf(fmaxf(0.2f*v + 0.5f, 0.f), 1.f); }

// ---------------- one-time: Wf = [Wc@Ww ; Uw]  (1536 x 2048), bf = bc@Ww + bw ----------------
__global__ __launch_bounds__(256) void wf_build(const float* __restrict__ Wc, const float* __restrict__ Ww,
                                                const float* __restrict__ Uw, float* __restrict__ Wf){
    int idx = blockIdx.x * 256 + threadIdx.x;   // k*2048 + j, k in [0,1536)
    int k = idx >> 11, j = idx & 2047;
    if (k < 2 * Dd){
        const float* wc = Wc + (size_t)k * Dd;
        float s = 0.f;
        for (int m = 0; m < Dd; ++m) s = fmaf(wc[m], Ww[(size_t)m * G4 + j], s);
        Wf[idx] = s;
    } else {
        Wf[idx] = Uw[(size_t)(k - 2 * Dd) * G4 + j];
    }
}

__global__ __launch_bounds__(256) void bf_build(const float* __restrict__ bc, const float* __restrict__ Ww,
                                                const float* __restrict__ bw, float* __restrict__ bf){
    int j = blockIdx.x * 256 + threadIdx.x;
    float s = bw[j];
    for (int m = 0; m < Dd; ++m) s = fmaf(bc[m], Ww[(size_t)m * G4 + j], s);
    bf[j] = s;
}

// ---------------- reader gate GEMM: part[ks][b][j] = sum_k [x_t,h][b,k] * [Wr;Ur][k,j] ----------------
// grid 256 = 64 j-tiles (32 wide) x 4 K-splits (Kc=256). block 256.
__global__ __launch_bounds__(256) void gemm_reader(const float* __restrict__ xt, const float* __restrict__ h,
                                                   const float* __restrict__ Wr, const float* __restrict__ Ur,
                                                   float* __restrict__ part){
    __shared__ float inT[64][65];
    __shared__ float wT[64][32];
    const int bx = blockIdx.x;
    const int jt = bx & 63, ks = bx >> 6;
    const int j0 = jt * 32;
    const int k0 = ks * 256;
    const int tid = threadIdx.x;
    const int tj4 = (tid & 7) * 4;
    const int tb  = tid >> 3;              // 0..31
    float a00=0.f,a01=0.f,a02=0.f,a03=0.f;
    float a10=0.f,a11=0.f,a12=0.f,a13=0.f;
    for (int kk = 0; kk < 256; kk += 64){
        #pragma unroll
        for (int i = 0; i < 16; ++i){
            int idx = tid + i * 256;
            int b = idx >> 6, k = idx & 63;
            int kg = k0 + kk + k;
            inT[b][k] = (kg < Dd) ? xt[(size_t)b * (Ll * Dd) + kg] : h[b * Dd + kg - Dd];
        }
        #pragma unroll
        for (int i = 0; i < 8; ++i){
            int idx = tid + i * 256;
            int k = idx >> 5, j = idx & 31;
            int kg = k0 + kk + k;
            wT[k][j] = (kg < Dd) ? Wr[(size_t)kg * G4 + j0 + j] : Ur[(size_t)(kg - Dd) * G4 + j0 + j];
        }
        __syncthreads();
        #pragma unroll 8
        for (int k = 0; k < 64; ++k){
            float4 wv = *(const float4*)&wT[k][tj4];
            float i0 = inT[tb][k];
            float i1 = inT[tb + 32][k];
            a00 = fmaf(i0, wv.x, a00); a01 = fmaf(i0, wv.y, a01);
            a02 = fmaf(i0, wv.z, a02); a03 = fmaf(i0, wv.w, a03);
            a10 = fmaf(i1, wv.x, a10); a11 = fmaf(i1, wv.y, a11);
            a12 = fmaf(i1, wv.z, a12); a13 = fmaf(i1, wv.w, a13);
        }
        __syncthreads();
    }
    size_t o0 = (size_t)(ks * Bb + tb) * G4 + j0 + tj4;
    size_t o1 = (size_t)(ks * Bb + tb + 32) * G4 + j0 + tj4;
    *(float4*)&part[o0] = make_float4(a00, a01, a02, a03);
    *(float4*)&part[o1] = make_float4(a10, a11, a12, a13);
}

// ---------------- writer gate GEMM: in = [o, m_rt, hw] (K=1536), W = Wf ----------------
// grid 256 = 64 j-tiles x 4 K-splits (Kc=384).
__global__ __launch_bounds__(256) void gemm_writer(const float* __restrict__ o, const float* __restrict__ mrt,
                                                   const float* __restrict__ hw, const float* __restrict__ Wf,
                                                   float* __restrict__ part){
    __shared__ float inT[64][65];
    __shared__ float wT[64][32];
    const int bx = blockIdx.x;
    const int jt = bx & 63, ks = bx >> 6;
    const int j0 = jt * 32;
    const int k0 = ks * 384;
    const int tid = threadIdx.x;
    const int tj4 = (tid & 7) * 4;
    const int tb  = tid >> 3;
    float a00=0.f,a01=0.f,a02=0.f,a03=0.f;
    float a10=0.f,a11=0.f,a12=0.f,a13=0.f;
    for (int kk = 0; kk < 384; kk += 64){
        #pragma unroll
        for (int i = 0; i < 16; ++i){
            int idx = tid + i * 256;
            int b = idx >> 6, k = idx & 63;
            int kg = k0 + kk + k;
            float v;
            if (kg < Dd)           v = o[b * Dd + kg];
            else if (kg < 2 * Dd)  v = mrt[b * Dd + kg - Dd];
            else                   v = hw[b * Dd + kg - 2 * Dd];
            inT[b][k] = v;
        }
        #pragma unroll
        for (int i = 0; i < 8; ++i){
            int idx = tid + i * 256;
            int k = idx >> 5, j = idx & 31;
            int kg = k0 + kk + k;
            wT[k][j] = Wf[(size_t)kg * G4 + j0 + j];
        }
        __syncthreads();
        #pragma unroll 8
        for (int k = 0; k < 64; ++k){
            float4 wv = *(const float4*)&wT[k][tj4];
            float i0 = inT[tb][k];
            float i1 = inT[tb + 32][k];
            a00 = fmaf(i0, wv.x, a00); a01 = fmaf(i0, wv.y, a01);
            a02 = fmaf(i0, wv.z, a02); a03 = fmaf(i0, wv.w, a03);
            a10 = fmaf(i1, wv.x, a10); a11 = fmaf(i1, wv.y, a11);
            a12 = fmaf(i1, wv.z, a12); a13 = fmaf(i1, wv.w, a13);
        }
        __syncthreads();
    }
    size_t o0 = (size_t)(ks * Bb + tb) * G4 + j0 + tj4;
    size_t o1 = (size_t)(ks * Bb + tb + 32) * G4 + j0 + tj4;
    *(float4*)&part[o0] = make_float4(a00, a01, a02, a03);
    *(float4*)&part[o1] = make_float4(a10, a11, a12, a13);
}

// ---------------- K-split reduce + LSTM pointwise (reader) ----------------
__global__ __launch_bounds__(256) void reader_pw(const float* __restrict__ part, const float* __restrict__ br,
                                                 float* __restrict__ h, float* __restrict__ c){
    int idx = blockIdx.x * 256 + threadIdx.x;      // b*512 + d
    int b = idx >> 9, d = idx & 511;
    float z[4];
    #pragma unroll
    for (int g = 0; g < 4; ++g){
        int j = g * Dd + d;
        float s = br[j];
        #pragma unroll
        for (int ks = 0; ks < 4; ++ks) s += part[(size_t)(ks * Bb + b) * G4 + j];
        z[g] = s;
    }
    float i = hsig(z[0]), f = hsig(z[1]), g2 = tanhf(z[2]), o = hsig(z[3]);
    float cn = fmaf(f, c[idx], i * g2);
    c[idx] = cn;
    h[idx] = o * tanhf(cn);
}

// ---------------- K-split reduce + LSTM pointwise (writer) ----------------
__global__ __launch_bounds__(256) void writer_pw(const float* __restrict__ part, const float* __restrict__ bf,
                                                 float* __restrict__ hw, float* __restrict__ cw,
                                                 float* __restrict__ out, int last){
    int idx = blockIdx.x * 256 + threadIdx.x;
    int b = idx >> 9, d = idx & 511;
    float z[4];
    #pragma unroll
    for (int g = 0; g < 4; ++g){
        int j = g * Dd + d;
        float s = bf[j];
        #pragma unroll
        for (int ks = 0; ks < 4; ++ks) s += part[(size_t)(ks * Bb + b) * G4 + j];
        z[g] = s;
    }
    float i = hsig(z[0]), f = hsig(z[1]), g2 = tanhf(z[2]), o = hsig(z[3]);
    float cn = fmaf(f, cw[idx], i * g2);
    cw[idx] = cn;
    float hn = o * tanhf(cn);
    hw[idx] = hn;
    if (last) out[idx] = hn;
}

// ---------------- MEGA: mem update (step t-1) + scores(t) + online-softmax weighted read ----------------
// grid 1024 = 64 b x 16, block 256 (4 waves). wave handles 16 rows (l), lane owns d = 4*lane..+3 and 256+4*lane..+3.
__global__ __launch_bounds__(256) void mega(const float* memIn, float* memOut,
                                            const float* __restrict__ o, const float* __restrict__ hw,
                                            float* scores, const float* __restrict__ Mb,
                                            const float* __restrict__ Sinv,
                                            float* __restrict__ part, int mode){
    const int bid = blockIdx.x;
    const int b = bid >> 4, lb = bid & 15;
    const int tid = threadIdx.x;
    const int lane = tid & 63;
    const int gw = lb * 4 + (tid >> 6);     // 0..63
    const int d0 = lane * 4, d1 = 256 + lane * 4;
    float4 oa = *(const float4*)(o + b * Dd + d0);
    float4 obv = *(const float4*)(o + b * Dd + d1);
    float4 ha = make_float4(0.f,0.f,0.f,0.f), hb = make_float4(0.f,0.f,0.f,0.f);
    float Mp = 0.f, Sip = 0.f;
    if (mode){
        ha = *(const float4*)(hw + b * Dd + d0);
        hb = *(const float4*)(hw + b * Dd + d1);
        Mp = Mb[b]; Sip = Sinv[b];
    }
    float m = -INFINITY, ssum = 0.f;
    float a0x=0.f,a0y=0.f,a0z=0.f,a0w=0.f, a1x=0.f,a1y=0.f,a1z=0.f,a1w=0.f;
    const int lbase = gw * 16;
    for (int r = 0; r < 16; ++r){
        const int l = lbase + r;
        const size_t base = ((size_t)b * Ll + l) * Dd;
        float4 v0 = *(const float4*)(memIn + base + d0);
        float4 v1 = *(const float4*)(memIn + base + d1);
        if (mode){
            float zp = __expf(scores[b * Ll + l] - Mp) * Sip;
            float om = 1.f - zp;
            v0.x = fmaf(v0.x, om, ha.x * zp); v0.y = fmaf(v0.y, om, ha.y * zp);
            v0.z = fmaf(v0.z, om, ha.z * zp); v0.w = fmaf(v0.w, om, ha.w * zp);
            v1.x = fmaf(v1.x, om, hb.x * zp); v1.y = fmaf(v1.y, om, hb.y * zp);
            v1.z = fmaf(v1.z, om, hb.z * zp); v1.w = fmaf(v1.w, om, hb.w * zp);
            *(float4*)(memOut + base + d0) = v0;
            *(float4*)(memOut + base + d1) = v1;
        }
        float s = v0.x*oa.x + v0.y*oa.y + v0.z*oa.z + v0.w*oa.w
                + v1.x*obv.x + v1.y*obv.y + v1.z*obv.z + v1.w*obv.w;
        #pragma unroll
        for (int off = 32; off; off >>= 1) s += __shfl_xor(s, off);
        if (lane == 0) scores[b * Ll + l] = s;
        float nm = fmaxf(m, s);
        float sc = __expf(m - nm);
        float wt = __expf(s - nm);
        ssum = fmaf(ssum, sc, wt);
        a0x = fmaf(a0x, sc, v0.x * wt); a0y = fmaf(a0y, sc, v0.y * wt);
        a0z = fmaf(a0z, sc, v0.z * wt); a0w = fmaf(a0w, sc, v0.w * wt);
        a1x = fmaf(a1x, sc, v1.x * wt); a1y = fmaf(a1y, sc, v1.y * wt);
        a1z = fmaf(a1z, sc, v1.z * wt); a1w = fmaf(a1w, sc, v1.w * wt);
        m = nm;
    }
    float* p = part + (size_t)(b * 64 + gw) * PART_STRIDE;
    *(float4*)(p + d0) = make_float4(a0x, a0y, a0z, a0w);
    *(float4*)(p + d1) = make_float4(a1x, a1y, a1z, a1w);
    if (lane == 0){ p[512] = m; p[513] = ssum; }
}

// ---------------- finalize: combine 64 wave partials per b -> m_rt, M, 1/S ----------------
__global__ __launch_bounds__(256) void small_a(const float* __restrict__ part, float* __restrict__ mrt,
                                               float* __restrict__ Mb, float* __restrict__ Sinv){
    const int b = blockIdx.x;
    const int tid = threadIdx.x;
    __shared__ float ews[64];
    if (tid < 64){
        const float* p = part + (size_t)(b * 64 + tid) * PART_STRIDE;
        float mw = p[512], sw = p[513];
        float M = mw;
        #pragma unroll
        for (int off = 32; off; off >>= 1) M = fmaxf(M, __shfl_xor(M, off));
        float e = __expf(mw - M);
        float Ssum = sw * e;
        #pragma unroll
        for (int off = 32; off; off >>= 1) Ssum += __shfl_xor(Ssum, off);
        float Si = 1.f / Ssum;
        ews[tid] = e * Si;
        if (tid == 0){ Mb[b] = M; Sinv[b] = Si; }
    }
    __syncthreads();
    for (int d = tid; d < Dd; d += 256){
        float s = 0.f;
        #pragma unroll 8
        for (int w2 = 0; w2 < 64; ++w2)
            s = fmaf(part[(size_t)(b * 64 + w2) * PART_STRIDE + d], ews[w2], s);
        mrt[b * Dd + d] = s;
    }
}

extern "C" void kernel_launch(void* const* d_in, const int* in_sizes, int n_in,
                              void* d_out, int out_size, void* d_ws, size_t ws_size,
                              hipStream_t stream) {
    (void)in_sizes; (void)n_in; (void)out_size;
    const float* x  = (const float*)d_in[0];
    const float* Wr = (const float*)d_in[1];
    const float* Ur = (const float*)d_in[2];
    const float* br = (const float*)d_in[3];
    const float* Ww = (const float*)d_in[4];
    const float* Uw = (const float*)d_in[5];
    const float* bw = (const float*)d_in[6];
    const float* Wc = (const float*)d_in[7];
    const float* bc = (const float*)d_in[8];
    float* out = (float*)d_out;

    float* w = (float*)d_ws;
    float* mem     = w; w += (size_t)Bb * Ll * Dd;        // 33,554,432
    float* scores  = w; w += (size_t)Bb * Ll;             // 65,536
    float* part_me = w; w += (size_t)Bb * 64 * PART_STRIDE; // 2,129,920
    float* Mb      = w; w += 64;
    float* Sinv    = w; w += 64;
    float* mrt     = w; w += (size_t)Bb * Dd;             // 32,768
    float* h_r     = w; w += (size_t)Bb * Dd;             // states: contiguous block of 4
    float* c_r     = w; w += (size_t)Bb * Dd;
    float* hw      = w; w += (size_t)Bb * Dd;
    float* cw      = w; w += (size_t)Bb * Dd;
    float* partR   = w; w += (size_t)4 * Bb * G4;         // 524,288
    float* partW   = w; w += (size_t)4 * Bb * G4;         // 524,288
    float* Wf      = w; w += (size_t)1536 * G4;           // 3,145,728
    float* bf      = w; w += G4;
    size_t need = (size_t)(w - (float*)d_ws) * sizeof(float);
    if (ws_size < need) return;   // workspace too small; bail

    // zero LSTM states (h_r, c_r, hw, cw are contiguous)
    hipMemsetAsync(h_r, 0, (size_t)4 * Bb * Dd * sizeof(float), stream);
    // fused writer weights
    wf_build<<<(1536 * G4) / 256, 256, 0, stream>>>(Wc, Ww, Uw, Wf);
    bf_build<<<G4 / 256, 256, 0, stream>>>(bc, Ww, bw, bf);

    for (int t = 0; t < Ll; ++t){
        gemm_reader<<<256, 256, 0, stream>>>(x + (size_t)t * Dd, h_r, Wr, Ur, partR);
        reader_pw<<<128, 256, 0, stream>>>(partR, br, h_r, c_r);
        const float* mi = (t <= 1) ? x : mem;
        mega<<<1024, 256, 0, stream>>>(mi, mem, h_r, hw, scores, Mb, Sinv, part_me, t == 0 ? 0 : 1);
        small_a<<<64, 256, 0, stream>>>(part_me, mrt, Mb, Sinv);
        gemm_writer<<<256, 256, 0, stream>>>(h_r, mrt, hw, Wf, partW);
        writer_pw<<<128, 256, 0, stream>>>(partW, bf, hw, cw, out, t == Ll - 1 ? 1 : 0);
    }
}